// Round 5
// baseline (247.069 us; speedup 1.0000x reference)
//
#include <hip/hip_runtime.h>

#define NROWS 256
#define LROW  65536
#define TOT   ((size_t)NROWS * LROW)
#define BLOCK 512
#define VPT   16
#define TILE  (BLOCK * VPT)       // 8192
#define TPR   (LROW / TILE)       // 8 tiles per row
#define NTILE (NROWS * TPR)       // 2048 blocks

// out[j] = (K0 + prefix_excl(inc)[j] + 2000) / 4000
// inc[j] = stress(t[j]) * (t[j+1]-t[j]),  t = 500*x
// stress(t) = a*exp(-t/(|c|+1e-3)) + b*log1p(t) + d*R*P/T
// Folded: a*exp2(t*ec) + pb2*log2(1+t) + cterm, ec=-1.4427/(|c|+1e-3), pb2=b*ln2

__global__ __launch_bounds__(BLOCK)
void stf_scan2(const float* __restrict__ x,
               const float* __restrict__ params,
               const float* __restrict__ k0v,
               const float* __restrict__ procc,
               float* __restrict__ out,
               unsigned long long* __restrict__ state)
{
    const int bid  = blockIdx.x;
    const int d    = bid >> 3;        // TPR = 8
    const int sub  = bid & 7;
    const int tid  = threadIdx.x;
    const int lane = tid & 63;
    const int wid  = tid >> 6;        // 0..7

    // per-row constants
    const float pa  = params[d * 4 + 0];
    const float pb  = params[d * 4 + 1];
    const float pcc = params[d * 4 + 2];
    const float pd  = params[d * 4 + 3];
    const float R   = procc[d * 4 + 0];
    const float T   = procc[d * 4 + 1] + 0.1f;
    const float P   = procc[d * 4 + 2];
    const float ec    = -1.44269504f / (fabsf(pcc) + 0.001f);
    const float pb2   = pb * 0.69314718f;
    const float cterm = pd * R * P / T;
    const float k0    = k0v[d];

    const size_t row0 = (size_t)d * LROW;
    const int    g0   = sub * TILE + tid * VPT;   // row-local first owned index
    const float* __restrict__ xp = x + row0 + g0;

    // ---- load 16 owned elements + boundary ----
    float4 c0 = *(const float4*)(xp + 0);
    float4 c1 = *(const float4*)(xp + 4);
    float4 c2 = *(const float4*)(xp + 8);
    float4 c3 = *(const float4*)(xp + 12);
    float xb = 0.0f;
    if (lane == 63) {
        const size_t gi = row0 + g0 + VPT;
        if (gi < TOT) xb = x[gi];      // cross-wave / cross-tile boundary
    }
    float xn = __shfl_down(c0.x, 1);   // next thread's first element
    if (lane == 63) xn = xb;

    float tv[VPT + 1];
    tv[0]  = c0.x * 500.0f; tv[1]  = c0.y * 500.0f; tv[2]  = c0.z * 500.0f; tv[3]  = c0.w * 500.0f;
    tv[4]  = c1.x * 500.0f; tv[5]  = c1.y * 500.0f; tv[6]  = c1.z * 500.0f; tv[7]  = c1.w * 500.0f;
    tv[8]  = c2.x * 500.0f; tv[9]  = c2.y * 500.0f; tv[10] = c2.z * 500.0f; tv[11] = c2.w * 500.0f;
    tv[12] = c3.x * 500.0f; tv[13] = c3.y * 500.0f; tv[14] = c3.z * 500.0f; tv[15] = c3.w * 500.0f;
    tv[16] = xn * 500.0f;

    // last increment of each ROW (j = 65535) does not exist -> zero it
    const bool isLast = (sub == TPR - 1) && (tid == BLOCK - 1);

    // ---- per-thread increments + local inclusive scan ----
    float pref[VPT];
    float run = 0.0f;
    #pragma unroll
    for (int k = 0; k < VPT; ++k) {
        const float t0 = tv[k];
        const float st = pa * exp2f(t0 * ec) + pb2 * __log2f(1.0f + t0) + cterm;
        float inc = st * (tv[k + 1] - t0);
        if (k == VPT - 1) inc = isLast ? 0.0f : inc;
        run += inc;
        pref[k] = run;
    }

    // ---- wave inclusive scan of per-thread sums ----
    float v = run;
    #pragma unroll
    for (int off = 1; off < 64; off <<= 1) {
        const float other = __shfl_up(v, off);
        if (lane >= off) v += other;
    }
    const float waveExcl = v - run;

    // ---- block scan of 8 wave totals + publish + lookback (wave 0) ----
    __shared__ float wtot[8];
    __shared__ float wexcl[8];
    __shared__ float s_carry;
    if (lane == 63) wtot[wid] = v;
    __syncthreads();

    if (wid == 0) {
        float wv = (lane < 8) ? wtot[lane] : 0.0f;
        float iv = wv;
        #pragma unroll
        for (int off = 1; off < 8; off <<= 1) {
            const float o = __shfl_up(iv, off);
            if (lane >= off && lane < 8) iv += o;
        }
        if (lane < 8) wexcl[lane] = iv - wv;
        const float total = __shfl(iv, 7);

        if (lane == 0) {
            const unsigned long long packed =
                0x100000000ull | (unsigned long long)__float_as_uint(total);
            __hip_atomic_store(&state[bid], packed,
                               __ATOMIC_RELEASE, __HIP_MEMORY_SCOPE_AGENT);
        }

        // lookback: sum aggregates of the <=7 preceding tiles of this row
        float c = 0.0f;
        if (lane < sub) {
            const int pt = bid - 1 - lane;
            unsigned long long w;
            do {
                w = __hip_atomic_load(&state[pt],
                                      __ATOMIC_ACQUIRE, __HIP_MEMORY_SCOPE_AGENT);
            } while (!(w >> 32));
            c = __uint_as_float((unsigned)w);
        }
        #pragma unroll
        for (int off = 1; off < 8; off <<= 1) c += __shfl_xor(c, off);
        if (lane == 0) s_carry = c;
    }
    __syncthreads();

    // ---- epilogue: out = (k0 + prefix)*(1/4000) + 0.5 ----
    const float sc    = 2.5e-4f;
    const float obase = (k0 + s_carry + wexcl[wid] + waveExcl) * sc + 0.5f;

    float4 o0, o1, o2, o3;
    o0.x = obase;
    o0.y = fmaf(pref[0],  sc, obase);
    o0.z = fmaf(pref[1],  sc, obase);
    o0.w = fmaf(pref[2],  sc, obase);
    o1.x = fmaf(pref[3],  sc, obase);
    o1.y = fmaf(pref[4],  sc, obase);
    o1.z = fmaf(pref[5],  sc, obase);
    o1.w = fmaf(pref[6],  sc, obase);
    o2.x = fmaf(pref[7],  sc, obase);
    o2.y = fmaf(pref[8],  sc, obase);
    o2.z = fmaf(pref[9],  sc, obase);
    o2.w = fmaf(pref[10], sc, obase);
    o3.x = fmaf(pref[11], sc, obase);
    o3.y = fmaf(pref[12], sc, obase);
    o3.z = fmaf(pref[13], sc, obase);
    o3.w = fmaf(pref[14], sc, obase);

    float* __restrict__ op = out + row0 + g0;
    *(float4*)(op + 0)  = o0;
    *(float4*)(op + 4)  = o1;
    *(float4*)(op + 8)  = o2;
    *(float4*)(op + 12) = o3;
}

extern "C" void kernel_launch(void* const* d_in, const int* in_sizes, int n_in,
                              void* d_out, int out_size, void* d_ws, size_t ws_size,
                              hipStream_t stream) {
    const float* x      = (const float*)d_in[0];   // [256*65536]
    const float* params = (const float*)d_in[1];   // [256,4]
    const float* K0     = (const float*)d_in[2];   // [256]
    const float* procc  = (const float*)d_in[3];   // [256,4]
    float* out = (float*)d_out;
    unsigned long long* state = (unsigned long long*)d_ws;

    // d_ws is poisoned 0xAA before every launch -> flags must be cleared.
    hipMemsetAsync(d_ws, 0, NTILE * sizeof(unsigned long long), stream);
    stf_scan2<<<NTILE, BLOCK, 0, stream>>>(x, params, K0, procc, out, state);
}

// Round 7
// 130.763 us; speedup vs baseline: 1.8894x; 1.8894x over previous
//
#include <hip/hip_runtime.h>

#define NROWS 256
#define LROW  65536
#define TOT   ((size_t)NROWS * LROW)
#define BLOCK 512
#define VPT   16
#define TILE  (BLOCK * VPT)       // 8192
#define TPR   (LROW / TILE)       // 8 tiles per row
#define NTILE (NROWS * TPR)       // 2048 blocks

// out[j] = (K0 + prefix_excl(inc)[j] + 2000) / 4000
// inc[j] = stress(t[j]) * (t[j+1]-t[j]),  t = 500*x
// stress(t) = a*exp(-t/(|c|+1e-3)) + b*log1p(t) + d*R*P/T
//
// Decoupled lookback with RELAXED packed {flag,value} atomics.
// Round-5 lesson: ACQUIRE/RELEASE at agent scope emit per-XCD L2
// invalidate/writeback on every access -> 163us all-idle stall. The flag and
// value share one 64-bit word, so relaxed atomics are sufficient (no other
// memory needs ordering).

__global__ __launch_bounds__(BLOCK)
void stf_scan3(const float* __restrict__ x,
               const float* __restrict__ params,
               const float* __restrict__ k0v,
               const float* __restrict__ procc,
               float* __restrict__ out,
               unsigned long long* __restrict__ state)
{
    const int bid  = blockIdx.x;
    const int d    = bid >> 3;        // TPR = 8
    const int sub  = bid & 7;
    const int tid  = threadIdx.x;
    const int lane = tid & 63;
    const int wid  = tid >> 6;        // 0..7

    // per-row constants
    const float pa  = params[d * 4 + 0];
    const float pb  = params[d * 4 + 1];
    const float pcc = params[d * 4 + 2];
    const float pd  = params[d * 4 + 3];
    const float R   = procc[d * 4 + 0];
    const float T   = procc[d * 4 + 1] + 0.1f;
    const float P   = procc[d * 4 + 2];
    const float ec    = -1.44269504f / (fabsf(pcc) + 0.001f);
    const float pb2   = pb * 0.69314718f;
    const float cterm = pd * R * P / T;
    const float k0    = k0v[d];

    const size_t row0 = (size_t)d * LROW;
    const int    g0   = sub * TILE + tid * VPT;   // row-local first owned index
    const float* __restrict__ xp = x + row0 + g0;

    // ---- load 16 owned elements + boundary ----
    float4 c0 = *(const float4*)(xp + 0);
    float4 c1 = *(const float4*)(xp + 4);
    float4 c2 = *(const float4*)(xp + 8);
    float4 c3 = *(const float4*)(xp + 12);
    float xb = 0.0f;
    if (lane == 63) {
        const size_t gi = row0 + g0 + VPT;
        if (gi < TOT) xb = x[gi];      // cross-wave / cross-tile boundary
    }
    float xn = __shfl_down(c0.x, 1);   // next thread's first element
    if (lane == 63) xn = xb;

    float tv[VPT + 1];
    tv[0]  = c0.x * 500.0f; tv[1]  = c0.y * 500.0f; tv[2]  = c0.z * 500.0f; tv[3]  = c0.w * 500.0f;
    tv[4]  = c1.x * 500.0f; tv[5]  = c1.y * 500.0f; tv[6]  = c1.z * 500.0f; tv[7]  = c1.w * 500.0f;
    tv[8]  = c2.x * 500.0f; tv[9]  = c2.y * 500.0f; tv[10] = c2.z * 500.0f; tv[11] = c2.w * 500.0f;
    tv[12] = c3.x * 500.0f; tv[13] = c3.y * 500.0f; tv[14] = c3.z * 500.0f; tv[15] = c3.w * 500.0f;
    tv[16] = xn * 500.0f;

    // last increment of each ROW (j = 65535) does not exist -> zero it
    const bool isLast = (sub == TPR - 1) && (tid == BLOCK - 1);

    // ---- per-thread increments + local inclusive scan ----
    float pref[VPT];
    float run = 0.0f;
    #pragma unroll
    for (int k = 0; k < VPT; ++k) {
        const float t0 = tv[k];
        const float st = pa * exp2f(t0 * ec) + pb2 * __log2f(1.0f + t0) + cterm;
        float inc = st * (tv[k + 1] - t0);
        if (k == VPT - 1) inc = isLast ? 0.0f : inc;
        run += inc;
        pref[k] = run;
    }

    // ---- wave inclusive scan of per-thread sums ----
    float v = run;
    #pragma unroll
    for (int off = 1; off < 64; off <<= 1) {
        const float other = __shfl_up(v, off);
        if (lane >= off) v += other;
    }
    const float waveExcl = v - run;

    // ---- block scan of 8 wave totals + publish + lookback (wave 0) ----
    __shared__ float wtot[8];
    __shared__ float wexcl[8];
    __shared__ float s_carry;
    if (lane == 63) wtot[wid] = v;
    __syncthreads();

    if (wid == 0) {
        float wv = (lane < 8) ? wtot[lane] : 0.0f;
        float iv = wv;
        #pragma unroll
        for (int off = 1; off < 8; off <<= 1) {
            const float o = __shfl_up(iv, off);
            if (lane >= off && lane < 8) iv += o;
        }
        if (lane < 8) wexcl[lane] = iv - wv;
        const float total = __shfl(iv, 7);

        if (lane == 0) {
            const unsigned long long packed =
                0x100000000ull | (unsigned long long)__float_as_uint(total);
            // RELAXED: flag+value share one word; no ordering fences needed.
            __hip_atomic_store(&state[bid], packed,
                               __ATOMIC_RELAXED, __HIP_MEMORY_SCOPE_AGENT);
        }

        // lookback: sum aggregates of the <=7 preceding tiles of this row
        float c = 0.0f;
        if (lane < sub) {
            const int pt = bid - 1 - lane;
            unsigned long long w;
            for (;;) {
                w = __hip_atomic_load(&state[pt],
                                      __ATOMIC_RELAXED, __HIP_MEMORY_SCOPE_AGENT);
                if (w >> 32) break;
                __builtin_amdgcn_s_sleep(2);
            }
            c = __uint_as_float((unsigned)w);
        }
        #pragma unroll
        for (int off = 1; off < 8; off <<= 1) c += __shfl_xor(c, off);
        if (lane == 0) s_carry = c;
    }
    __syncthreads();

    // ---- epilogue: out = (k0 + prefix)*(1/4000) + 0.5 ----
    const float sc    = 2.5e-4f;
    const float obase = (k0 + s_carry + wexcl[wid] + waveExcl) * sc + 0.5f;

    float4 o0, o1, o2, o3;
    o0.x = obase;
    o0.y = fmaf(pref[0],  sc, obase);
    o0.z = fmaf(pref[1],  sc, obase);
    o0.w = fmaf(pref[2],  sc, obase);
    o1.x = fmaf(pref[3],  sc, obase);
    o1.y = fmaf(pref[4],  sc, obase);
    o1.z = fmaf(pref[5],  sc, obase);
    o1.w = fmaf(pref[6],  sc, obase);
    o2.x = fmaf(pref[7],  sc, obase);
    o2.y = fmaf(pref[8],  sc, obase);
    o2.z = fmaf(pref[9],  sc, obase);
    o2.w = fmaf(pref[10], sc, obase);
    o3.x = fmaf(pref[11], sc, obase);
    o3.y = fmaf(pref[12], sc, obase);
    o3.z = fmaf(pref[13], sc, obase);
    o3.w = fmaf(pref[14], sc, obase);

    float* __restrict__ op = out + row0 + g0;
    *(float4*)(op + 0)  = o0;
    *(float4*)(op + 4)  = o1;
    *(float4*)(op + 8)  = o2;
    *(float4*)(op + 12) = o3;
}

extern "C" void kernel_launch(void* const* d_in, const int* in_sizes, int n_in,
                              void* d_out, int out_size, void* d_ws, size_t ws_size,
                              hipStream_t stream) {
    const float* x      = (const float*)d_in[0];   // [256*65536]
    const float* params = (const float*)d_in[1];   // [256,4]
    const float* K0     = (const float*)d_in[2];   // [256]
    const float* procc  = (const float*)d_in[3];   // [256,4]
    float* out = (float*)d_out;
    unsigned long long* state = (unsigned long long*)d_ws;

    // d_ws is poisoned 0xAA before every launch -> flags must be cleared.
    hipMemsetAsync(d_ws, 0, NTILE * sizeof(unsigned long long), stream);
    stf_scan3<<<NTILE, BLOCK, 0, stream>>>(x, params, K0, procc, out, state);
}

// Round 10
// 121.808 us; speedup vs baseline: 2.0284x; 1.0735x over previous
//
#include <hip/hip_runtime.h>

#define NROWS 256
#define LROW  65536
#define TOT   ((size_t)NROWS * LROW)
#define BLOCK 512
#define VPT   16
#define TILE  (BLOCK * VPT)       // 8192 elements, 32KB
#define TPR   (LROW / TILE)       // 8 tiles per row
#define NTILE (NROWS * TPR)       // 2048 blocks

// out[j] = (K0 + prefix_excl(inc)[j] + 2000) / 4000
// inc[j] = stress(t[j]) * (t[j+1]-t[j]),  t = 500*x
// stress(t) = a*exp2(t*ec) + pb2*log2(1+t) + cterm
//
// Round-7 lesson: per-thread-consecutive float4 I/O puts 64 lanes 64B apart
// -> 64 cachelines per instruction -> ~2.4 TB/s ceiling (round3 and round7
// both pinned at 41.6us). This version stages the tile through LDS so every
// GLOBAL access is perfectly coalesced (lane i at base+16i); the scan keeps
// the per-thread-consecutive ownership via swizzled LDS.
// LDS swizzle (float-index): e ^ (((e>>4)&3)<<2) -- involution, preserves
// 16B alignment; coalesced phase = conflict-free, strided phase = 2-way (free).

__device__ __forceinline__ int sw(int e) { return e ^ (((e >> 4) & 3) << 2); }

__global__ __launch_bounds__(BLOCK)
void stf_scan5(const float* __restrict__ x,
               const float* __restrict__ params,
               const float* __restrict__ k0v,
               const float* __restrict__ procc,
               float* __restrict__ out,
               unsigned long long* __restrict__ state)
{
    const int bid  = blockIdx.x;
    const int d    = bid >> 3;        // TPR = 8
    const int sub  = bid & 7;
    const int tid  = threadIdx.x;
    const int lane = tid & 63;
    const int wid  = tid >> 6;        // 0..7

    __shared__ float tile[TILE];      // 32KB, swizzled element store
    __shared__ float baseArr[BLOCK];
    __shared__ float wtot[8];
    __shared__ float wexcl[8];
    __shared__ float s_carry;

    // per-row constants
    const float pa  = params[d * 4 + 0];
    const float pb  = params[d * 4 + 1];
    const float pcc = params[d * 4 + 2];
    const float pd  = params[d * 4 + 3];
    const float R   = procc[d * 4 + 0];
    const float T   = procc[d * 4 + 1] + 0.1f;
    const float P   = procc[d * 4 + 2];
    const float ec    = -1.44269504f / (fabsf(pcc) + 0.001f);
    const float pb2   = pb * 0.69314718f;
    const float cterm = pd * R * P / T;
    const float k0    = k0v[d];

    const size_t tbase = (size_t)d * LROW + (size_t)sub * TILE;

    // ---- phase 1: fully coalesced global loads (lane i at +16B*i) ----
    const float* __restrict__ xp = x + tbase + tid * 4;
    float4 L0 = *(const float4*)(xp + 0 * 2048);
    float4 L1 = *(const float4*)(xp + 1 * 2048);
    float4 L2 = *(const float4*)(xp + 2 * 2048);
    float4 L3 = *(const float4*)(xp + 3 * 2048);
    float bxg = 0.0f;                 // cross-tile boundary (last thread only)
    if (tid == BLOCK - 1) {
        const size_t gi = tbase + TILE;
        if (gi < TOT) bxg = x[gi];
    }

    // ---- phase 2: stage to LDS (swizzled) ----
    *(float4*)&tile[sw(0 * 2048 + tid * 4)] = L0;
    *(float4*)&tile[sw(1 * 2048 + tid * 4)] = L1;
    *(float4*)&tile[sw(2 * 2048 + tid * 4)] = L2;
    *(float4*)&tile[sw(3 * 2048 + tid * 4)] = L3;
    __syncthreads();                  // A: tile fully staged

    // boundary element (first elem of next thread's run) -- must be read
    // before anyone overwrites their slots with scan values
    const float bnd = (tid < BLOCK - 1) ? tile[sw((tid + 1) * VPT)] : bxg;
    __syncthreads();                  // B: boundary reads done

    // ---- phase 3: streamed local scan; overwrite own slots with s-values ----
    // slot e=16*tid+k receives s[k] = pref[k-1] (s[0]=0); reader adds base.
    const int eb = tid * VPT;
    float4 cur = *(const float4*)&tile[sw(eb)];
    float run = 0.0f, sprev = 0.0f;
    #pragma unroll
    for (int g = 0; g < 4; ++g) {
        float4 nxt;
        if (g < 3) nxt = *(const float4*)&tile[sw(eb + 4 * (g + 1))];
        else       nxt = make_float4(bnd, 0.0f, 0.0f, 0.0f);

        const float ta = cur.x * 500.0f, tb = cur.y * 500.0f;
        const float tc = cur.z * 500.0f, td = cur.w * 500.0f;
        const float te = nxt.x * 500.0f;

        float4 s4;
        s4.x = sprev;   // pref[4g-1]
        run += (pa * exp2f(ta * ec) + pb2 * __log2f(1.0f + ta) + cterm) * (tb - ta);
        s4.y = run;     // pref[4g]
        run += (pa * exp2f(tb * ec) + pb2 * __log2f(1.0f + tb) + cterm) * (tc - tb);
        s4.z = run;     // pref[4g+1]
        run += (pa * exp2f(tc * ec) + pb2 * __log2f(1.0f + tc) + cterm) * (td - tc);
        s4.w = run;     // pref[4g+2]
        run += (pa * exp2f(td * ec) + pb2 * __log2f(1.0f + td) + cterm) * (te - td);
        sprev = run;    // pref[4g+3]

        *(float4*)&tile[sw(eb + 4 * g)] = s4;   // own slots only
        cur = nxt;
    }
    // NOTE: the final tile of a row computes a junk last increment (bnd=0 or
    // next row's value) but it only feeds this tile's published aggregate,
    // which has no successor -> never consumed.

    // ---- phase 4: wave inclusive scan of per-thread sums ----
    float v = run;
    #pragma unroll
    for (int off = 1; off < 64; off <<= 1) {
        const float o = __shfl_up(v, off);
        if (lane >= off) v += o;
    }
    const float waveExcl = v - run;
    if (lane == 63) wtot[wid] = v;
    __syncthreads();                  // C

    // ---- phase 5: block scan of 8 wave totals + publish + lookback ----
    if (wid == 0) {
        float wv = (lane < 8) ? wtot[lane] : 0.0f;
        float iv = wv;
        #pragma unroll
        for (int off = 1; off < 8; off <<= 1) {
            const float o = __shfl_up(iv, off);
            if (lane >= off && lane < 8) iv += o;
        }
        if (lane < 8) wexcl[lane] = iv - wv;
        const float total = __shfl(iv, 7);

        if (lane == 0) {
            const unsigned long long packed =
                0x100000000ull | (unsigned long long)__float_as_uint(total);
            // RELAXED only: flag+value share one word (round-5 lesson:
            // acquire/release at agent scope = per-XCD L2 flush storm).
            __hip_atomic_store(&state[bid], packed,
                               __ATOMIC_RELAXED, __HIP_MEMORY_SCOPE_AGENT);
        }
        float c = 0.0f;
        if (lane < sub) {
            const int pt = bid - 1 - lane;
            unsigned long long w;
            for (;;) {
                w = __hip_atomic_load(&state[pt],
                                      __ATOMIC_RELAXED, __HIP_MEMORY_SCOPE_AGENT);
                if (w >> 32) break;
                __builtin_amdgcn_s_sleep(2);
            }
            c = __uint_as_float((unsigned)w);
        }
        #pragma unroll
        for (int off = 1; off < 8; off <<= 1) c += __shfl_xor(c, off);
        if (lane == 0) s_carry = c;
    }
    __syncthreads();                  // D

    // ---- phase 6: per-producer base values ----
    baseArr[tid] = k0 + s_carry + wexcl[wid] + waveExcl;
    __syncthreads();                  // E

    // ---- phase 7: fully coalesced stores ----
    const float scl = 2.5e-4f;
    float* __restrict__ op = out + tbase + tid * 4;
    #pragma unroll
    for (int r = 0; r < 4; ++r) {
        const float4 sv = *(const float4*)&tile[sw(r * 2048 + tid * 4)];
        const float b = baseArr[r * 128 + (tid >> 2)];   // producer = e>>4
        float4 o;
        o.x = (sv.x + b) * scl + 0.5f;
        o.y = (sv.y + b) * scl + 0.5f;
        o.z = (sv.z + b) * scl + 0.5f;
        o.w = (sv.w + b) * scl + 0.5f;
        *(float4*)(op + r * 2048) = o;
    }
}

extern "C" void kernel_launch(void* const* d_in, const int* in_sizes, int n_in,
                              void* d_out, int out_size, void* d_ws, size_t ws_size,
                              hipStream_t stream) {
    const float* x      = (const float*)d_in[0];   // [256*65536]
    const float* params = (const float*)d_in[1];   // [256,4]
    const float* K0     = (const float*)d_in[2];   // [256]
    const float* procc  = (const float*)d_in[3];   // [256,4]
    float* out = (float*)d_out;
    unsigned long long* state = (unsigned long long*)d_ws;

    // d_ws is poisoned 0xAA before every launch -> flags must be cleared.
    hipMemsetAsync(d_ws, 0, NTILE * sizeof(unsigned long long), stream);
    stf_scan5<<<NTILE, BLOCK, 0, stream>>>(x, params, K0, procc, out, state);
}